// Round 1
// baseline (2342.736 us; speedup 1.0000x reference)
//
#include <hip/hip_runtime.h>

typedef __attribute__((ext_vector_type(8))) __bf16 bf16x8;
typedef __attribute__((ext_vector_type(4))) __bf16 bf16x4;
typedef __attribute__((ext_vector_type(4))) float f32x4;
typedef __attribute__((ext_vector_type(4))) unsigned short u16x4;

#define AS1 __attribute__((address_space(1)))
#define AS3 __attribute__((address_space(3)))

__device__ __forceinline__ void ld_g2l16(const __bf16* g, __bf16* l) {
    // 16B/lane direct global->LDS (guide m97: width=16). LDS dest must be
    // wave-uniform base; lane offset = lane*16 is implicit.
    __builtin_amdgcn_global_load_lds((AS1 void*)g, (AS3 void*)l, 16, 0, 0);
}

// ---------------------------------------------------------------------------
// C[m,n] = sum_k A[m,k]*B[n,k] + bias[n]   (A:[M,K], B:[N,K], both bf16)
// MODE 0: store bf16 to Cb.    MODE 1: xv = Cf[m,n]+v; Cf=xv (fp32); Cb=bf16(xv)
// 128x128 tile, BK=64, 4 waves in 2x2, each wave 4x4 of 16x16x32 MFMA tiles.
// ---------------------------------------------------------------------------
template<int MODE>
__global__ void gemm_bt(const __bf16* __restrict__ A, const __bf16* __restrict__ B,
                        const float* __restrict__ bias, __bf16* __restrict__ Cb,
                        float* __restrict__ Cf, int M, int N, int K)
{
    __shared__ __align__(16) __bf16 As[128 * 64];
    __shared__ __align__(16) __bf16 Bs[128 * 64];
    const int tid = threadIdx.x;
    const int wave = tid >> 6, lane = tid & 63;
    const int quad = lane >> 4, l15 = lane & 15;
    const int lrow = lane >> 3, lcol = lane & 7;
    const int m0 = blockIdx.y * 128, n0 = blockIdx.x * 128;
    const int wm = wave & 1, wn = wave >> 1;
    const __bf16* Ab = A + (size_t)m0 * K;
    const __bf16* Bb = B + (size_t)n0 * K;

    f32x4 acc[4][4] = {};

    for (int k0 = 0; k0 < K; k0 += 64) {
        __syncthreads();
        #pragma unroll
        for (int j = 0; j < 4; ++j) {
            const int chunk = wave * 4 + j;          // 16 chunks of 8 rows
            const int row = chunk * 8 + lrow;
            ld_g2l16(Ab + (size_t)row * K + k0 + lcol * 8, &As[chunk * 512]);
            ld_g2l16(Bb + (size_t)row * K + k0 + lcol * 8, &Bs[chunk * 512]);
        }
        __syncthreads();   // compiler drains vmcnt before s_barrier
        #pragma unroll
        for (int s = 0; s < 2; ++s) {
            bf16x8 af[4], bfr[4];
            #pragma unroll
            for (int r = 0; r < 4; ++r)
                af[r] = *(const bf16x8*)&As[(wm * 64 + r * 16 + l15) * 64 + s * 32 + quad * 8];
            #pragma unroll
            for (int c = 0; c < 4; ++c)
                bfr[c] = *(const bf16x8*)&Bs[(wn * 64 + c * 16 + l15) * 64 + s * 32 + quad * 8];
            #pragma unroll
            for (int r = 0; r < 4; ++r)
                #pragma unroll
                for (int c = 0; c < 4; ++c)
                    acc[r][c] = __builtin_amdgcn_mfma_f32_16x16x32_bf16(af[r], bfr[c], acc[r][c], 0, 0, 0);
        }
    }

    // C/D layout (measured m89/m91): col = lane&15, row = quad*4 + reg
    #pragma unroll
    for (int r = 0; r < 4; ++r) {
        #pragma unroll
        for (int c = 0; c < 4; ++c) {
            #pragma unroll
            for (int e = 0; e < 4; ++e) {
                const int m = m0 + wm * 64 + r * 16 + quad * 4 + e;
                const int n = n0 + wn * 64 + c * 16 + l15;
                const float v = acc[r][c][e] + bias[n];
                const size_t idx = (size_t)m * N + n;
                if (MODE == 0) {
                    Cb[idx] = (__bf16)v;
                } else {
                    const float xv = Cf[idx] + v;
                    Cf[idx] = xv;
                    Cb[idx] = (__bf16)xv;
                }
            }
        }
    }
}

// ---------------------------------------------------------------------------
// S kernel: St[bh][d2][d1] = scale * sum_t K[t,d1] * V[t,d2]    (64x64 per bh)
// One block per (b,h); chunk T by 128; LDS-transpose K,V to [d][t]; each wave
// owns a 16-row d1 slice over the full t range (no cross-wave reduction).
// ---------------------------------------------------------------------------
__global__ void s_kernel(const __bf16* __restrict__ qkv, __bf16* __restrict__ St)
{
    constexpr int CH = 128;
    __shared__ __align__(16) __bf16 Kt[64][CH + 8];
    __shared__ __align__(16) __bf16 Vt[64][CH + 8];
    const int bh = blockIdx.x;
    const int b = bh >> 4, h = bh & 15;
    const int tid = threadIdx.x;
    const int wave = tid >> 6, lane = tid & 63;
    const int quad = lane >> 4, l15 = lane & 15;
    const __bf16* Kbase = qkv + (size_t)b * 2048 * 3072 + 1024 + h * 64;
    const __bf16* Vbase = Kbase + 1024;

    f32x4 acc[4] = {};

    for (int t0 = 0; t0 < 2048; t0 += CH) {
        __syncthreads();
        for (int i = tid; i < CH * 16; i += 256) {
            const int t = i >> 4, d4 = (i & 15) * 4;
            union { u16x4 u; __bf16 b[4]; } kv, vv;
            kv.u = *(const u16x4*)(Kbase + (size_t)(t0 + t) * 3072 + d4);
            vv.u = *(const u16x4*)(Vbase + (size_t)(t0 + t) * 3072 + d4);
            #pragma unroll
            for (int j = 0; j < 4; ++j) {
                Kt[d4 + j][t] = kv.b[j];
                Vt[d4 + j][t] = vv.b[j];
            }
        }
        __syncthreads();
        #pragma unroll
        for (int s = 0; s < CH / 32; ++s) {
            const bf16x8 a = *(const bf16x8*)&Kt[wave * 16 + l15][s * 32 + quad * 8];
            #pragma unroll
            for (int c = 0; c < 4; ++c) {
                const bf16x8 bb = *(const bf16x8*)&Vt[c * 16 + l15][s * 32 + quad * 8];
                acc[c] = __builtin_amdgcn_mfma_f32_16x16x32_bf16(a, bb, acc[c], 0, 0, 0);
            }
        }
    }

    #pragma unroll
    for (int c = 0; c < 4; ++c) {
        bf16x4 o;
        #pragma unroll
        for (int e = 0; e < 4; ++e) o[e] = (__bf16)(acc[c][e] * 0.125f);
        // d1 = wave*16 + quad*4 + e (consecutive over e), d2 = c*16 + l15
        *(bf16x4*)&St[(size_t)bh * 4096 + (size_t)(c * 16 + l15) * 64 + wave * 16 + quad * 4] = o;
    }
}

// ---------------------------------------------------------------------------
// Y kernel: Y[b,t,h*64+d2] = sum_d1 Q[b,t,h,d1] * St[bh][d2][d1]
// Block = (t-tile of 256) x (b,h). Q staged via global_load_lds; St from L2.
// ---------------------------------------------------------------------------
__global__ void y_kernel(const __bf16* __restrict__ qkv, const __bf16* __restrict__ St,
                         __bf16* __restrict__ Y)
{
    __shared__ __align__(16) __bf16 Qs[256 * 64];
    const int bh = blockIdx.y, b = bh >> 4, h = bh & 15;
    const int t0 = blockIdx.x * 256;
    const int tid = threadIdx.x;
    const int wave = tid >> 6, lane = tid & 63;
    const int quad = lane >> 4, l15 = lane & 15;
    const int lrow = lane >> 3, lcol = lane & 7;
    const __bf16* Qb = qkv + ((size_t)b * 2048 + t0) * 3072 + h * 64;

    #pragma unroll
    for (int j = 0; j < 8; ++j) {
        const int chunk = wave * 8 + j;              // 32 chunks of 8 rows
        const int row = chunk * 8 + lrow;
        ld_g2l16(Qb + (size_t)row * 3072 + lcol * 8, &Qs[chunk * 512]);
    }

    f32x4 acc[4][4] = {};
    const __bf16* Sb = St + (size_t)bh * 4096;
    __syncthreads();
    #pragma unroll
    for (int s = 0; s < 2; ++s) {
        bf16x8 af[4], bfr[4];
        #pragma unroll
        for (int r = 0; r < 4; ++r)
            af[r] = *(const bf16x8*)&Qs[(wave * 64 + r * 16 + l15) * 64 + s * 32 + quad * 8];
        #pragma unroll
        for (int c = 0; c < 4; ++c)
            bfr[c] = *(const bf16x8*)&Sb[(size_t)(c * 16 + l15) * 64 + s * 32 + quad * 8];
        #pragma unroll
        for (int r = 0; r < 4; ++r)
            #pragma unroll
            for (int c = 0; c < 4; ++c)
                acc[r][c] = __builtin_amdgcn_mfma_f32_16x16x32_bf16(af[r], bfr[c], acc[r][c], 0, 0, 0);
    }

    #pragma unroll
    for (int r = 0; r < 4; ++r)
        #pragma unroll
        for (int c = 0; c < 4; ++c)
            #pragma unroll
            for (int e = 0; e < 4; ++e) {
                const int t = t0 + wave * 64 + r * 16 + quad * 4 + e;
                Y[((size_t)b * 2048 + t) * 1024 + h * 64 + c * 16 + l15] = (__bf16)acc[r][c][e];
            }
}

// ---------------------------------------------------------------------------
__global__ void cvt_bf16(const float* __restrict__ src, __bf16* __restrict__ dst, int n4)
{
    const int i = blockIdx.x * 256 + threadIdx.x;
    if (i >= n4) return;
    const float4 v = ((const float4*)src)[i];
    bf16x4 o = { (__bf16)v.x, (__bf16)v.y, (__bf16)v.z, (__bf16)v.w };
    ((bf16x4*)dst)[i] = o;
}

__global__ void init_x(const float* __restrict__ src, __bf16* __restrict__ xB,
                       float* __restrict__ xF, int n4)
{
    const int i = blockIdx.x * 256 + threadIdx.x;
    if (i >= n4) return;
    const float4 v = ((const float4*)src)[i];
    ((float4*)xF)[i] = v;
    bf16x4 o = { (__bf16)v.x, (__bf16)v.y, (__bf16)v.z, (__bf16)v.w };
    ((bf16x4*)xB)[i] = o;
}

// ---------------------------------------------------------------------------
extern "C" void kernel_launch(void* const* d_in, const int* in_sizes, int n_in,
                              void* d_out, int out_size, void* d_ws, size_t ws_size,
                              hipStream_t stream)
{
    const float* x0    = (const float*)d_in[0];   // [4,2048,1024]
    const float* Wqkv  = (const float*)d_in[1];   // [12,3072,1024]
    const float* bqkv  = (const float*)d_in[2];   // [12,3072]
    const float* Wproj = (const float*)d_in[3];   // [12,1024,1024]
    const float* bproj = (const float*)d_in[4];   // [12,1024]
    float* xF = (float*)d_out;                    // fp32 x lives in d_out

    char* p = (char*)d_ws;
    __bf16* WqkvB  = (__bf16*)p; p += (size_t)12 * 3072 * 1024 * 2;  // 75.5 MB
    __bf16* WprojB = (__bf16*)p; p += (size_t)12 * 1024 * 1024 * 2;  // 25.2 MB
    __bf16* xB     = (__bf16*)p; p += (size_t)8192 * 1024 * 2;       // 16.8 MB
    __bf16* qkv    = (__bf16*)p; p += (size_t)8192 * 3072 * 2;       // 50.3 MB
    __bf16* St     = (__bf16*)p; p += (size_t)64 * 4096 * 2;         // 0.5 MB
    __bf16* Y      = (__bf16*)p; p += (size_t)8192 * 1024 * 2;       // 16.8 MB

    cvt_bf16<<<36864, 256, 0, stream>>>(Wqkv, WqkvB, 9437184);
    cvt_bf16<<<12288, 256, 0, stream>>>(Wproj, WprojB, 3145728);
    init_x<<<8192, 256, 0, stream>>>(x0, xB, xF, 2097152);

    for (int i = 0; i < 12; ++i) {
        // qkv = x @ Wqkv^T + bqkv                      [8192,3072]
        gemm_bt<0><<<dim3(24, 64), 256, 0, stream>>>(
            xB, WqkvB + (size_t)i * 3072 * 1024, bqkv + i * 3072,
            qkv, nullptr, 8192, 3072, 1024);
        // St[bh] = scale * (K^T V), stored transposed  [64,64,64]
        s_kernel<<<64, 256, 0, stream>>>(qkv, St);
        // Y = Q @ S                                    [8192,1024]
        y_kernel<<<dim3(8, 64), 256, 0, stream>>>(qkv, St, Y);
        // x = x + Y @ Wproj^T + bproj  (fp32 master + bf16 copy)
        gemm_bt<1><<<dim3(8, 64), 256, 0, stream>>>(
            Y, WprojB + (size_t)i * 1024 * 1024, bproj + i * 1024,
            xB, xF, 8192, 1024, 1024);
    }
}

// Round 2
// 1907.405 us; speedup vs baseline: 1.2282x; 1.2282x over previous
//
#include <hip/hip_runtime.h>

typedef __attribute__((ext_vector_type(8))) __bf16 bf16x8;
typedef __attribute__((ext_vector_type(4))) __bf16 bf16x4;
typedef __attribute__((ext_vector_type(4))) float f32x4;
typedef __attribute__((ext_vector_type(4))) unsigned short u16x4;

#define AS1 __attribute__((address_space(1)))
#define AS3 __attribute__((address_space(3)))

__device__ __forceinline__ void ld_g2l16(const __bf16* g, __bf16* l) {
    // 16B/lane direct global->LDS (guide m97). LDS dest is wave-uniform base;
    // lane offset = lane*16 implicit.
    __builtin_amdgcn_global_load_lds((AS1 void*)g, (AS3 void*)l, 16, 0, 0);
}

// ---------------------------------------------------------------------------
// C[m,n] = sum_k A[m,k]*B[n,k] + bias[n]   (A:[M,K], B:[N,K], both bf16)
// MODE 0: store bf16 to Cb via LDS repack (16B/lane, 256B runs).
// MODE 1: xv = Cf[m,n]+v; Cf=xv (fp32); Cb=bf16(xv)  (scalar epilogue)
// 128x128 tile, BK=64, 4 waves 2x2, each wave 4x4 of 16x16x32 MFMA tiles.
// ---------------------------------------------------------------------------
template<int MODE>
__global__ void gemm_bt(const __bf16* __restrict__ A, const __bf16* __restrict__ B,
                        const float* __restrict__ bias, __bf16* __restrict__ Cb,
                        float* __restrict__ Cf, int M, int N, int K)
{
    // staging needs 2*128*64 = 16384 elts; MODE-0 epilogue reuses it as a
    // padded 128x136 bf16 tile (17408 elts = 34.8 KB) for vectorized stores.
    __shared__ __align__(16) __bf16 smem[17408];
    __bf16* As = smem;
    __bf16* Bs = smem + 128 * 64;
    const int tid = threadIdx.x;
    const int wave = tid >> 6, lane = tid & 63;
    const int quad = lane >> 4, l15 = lane & 15;
    const int lrow = lane >> 3, lcol = lane & 7;
    const int m0 = blockIdx.y * 128, n0 = blockIdx.x * 128;
    const int wm = wave & 1, wn = wave >> 1;
    const __bf16* Ab = A + (size_t)m0 * K;
    const __bf16* Bb = B + (size_t)n0 * K;

    f32x4 acc[4][4] = {};

    for (int k0 = 0; k0 < K; k0 += 64) {
        __syncthreads();
        #pragma unroll
        for (int j = 0; j < 4; ++j) {
            const int chunk = wave * 4 + j;          // 16 chunks of 8 rows
            const int row = chunk * 8 + lrow;
            ld_g2l16(Ab + (size_t)row * K + k0 + lcol * 8, &As[chunk * 512]);
            ld_g2l16(Bb + (size_t)row * K + k0 + lcol * 8, &Bs[chunk * 512]);
        }
        __syncthreads();
        #pragma unroll
        for (int s = 0; s < 2; ++s) {
            bf16x8 af[4], bfr[4];
            #pragma unroll
            for (int r = 0; r < 4; ++r)
                af[r] = *(const bf16x8*)&As[(wm * 64 + r * 16 + l15) * 64 + s * 32 + quad * 8];
            #pragma unroll
            for (int c = 0; c < 4; ++c)
                bfr[c] = *(const bf16x8*)&Bs[(wn * 64 + c * 16 + l15) * 64 + s * 32 + quad * 8];
            #pragma unroll
            for (int r = 0; r < 4; ++r)
                #pragma unroll
                for (int c = 0; c < 4; ++c)
                    acc[r][c] = __builtin_amdgcn_mfma_f32_16x16x32_bf16(af[r], bfr[c], acc[r][c], 0, 0, 0);
        }
    }

    // C/D layout (measured m89/m91): col = lane&15, row = quad*4 + reg
    if (MODE == 0) {
        __syncthreads();                      // all waves done reading As/Bs
        __bf16 (*Cs)[136] = (__bf16(*)[136])smem;
        #pragma unroll
        for (int r = 0; r < 4; ++r)
            #pragma unroll
            for (int c = 0; c < 4; ++c)
                #pragma unroll
                for (int e = 0; e < 4; ++e)
                    Cs[wm * 64 + r * 16 + quad * 4 + e][wn * 64 + c * 16 + l15] =
                        (__bf16)(acc[r][c][e] + bias[n0 + wn * 64 + c * 16 + l15]);
        __syncthreads();
        #pragma unroll
        for (int p = 0; p < 8; ++p) {
            const int i = p * 256 + tid;      // 2048 chunks of 16B
            const int row = i >> 4, ch = i & 15;
            *(bf16x8*)&Cb[(size_t)(m0 + row) * N + n0 + ch * 8] =
                *(const bf16x8*)&Cs[row][ch * 8];
        }
    } else {
        #pragma unroll
        for (int r = 0; r < 4; ++r)
            #pragma unroll
            for (int c = 0; c < 4; ++c)
                #pragma unroll
                for (int e = 0; e < 4; ++e) {
                    const int m = m0 + wm * 64 + r * 16 + quad * 4 + e;
                    const int n = n0 + wn * 64 + c * 16 + l15;
                    const float v = acc[r][c][e] + bias[n];
                    const size_t idx = (size_t)m * N + n;
                    const float xv = Cf[idx] + v;
                    Cf[idx] = xv;
                    Cb[idx] = (__bf16)xv;
                }
    }
}

// ---------------------------------------------------------------------------
// s_partial: P[ch][bh][d2*64+d1] = sum_{t in chunk} K[t,d1]*V[t,d2]  (fp32)
// grid (64 bh, 16 chunks) -> 1024 blocks (vs 64 before: chip now saturated).
// ---------------------------------------------------------------------------
__global__ void s_partial(const __bf16* __restrict__ qkv, float* __restrict__ P)
{
    constexpr int CH = 128;
    __shared__ __align__(16) __bf16 Kt[64][CH + 8];
    __shared__ __align__(16) __bf16 Vt[64][CH + 8];
    const int bh = blockIdx.x, chb = blockIdx.y;
    const int b = bh >> 4, h = bh & 15;
    const int t0 = chb * CH;
    const int tid = threadIdx.x;
    const int wave = tid >> 6, lane = tid & 63;
    const int quad = lane >> 4, l15 = lane & 15;
    const __bf16* Kbase = qkv + (size_t)b * 2048 * 3072 + 1024 + h * 64;
    const __bf16* Vbase = Kbase + 1024;

    for (int i = tid; i < CH * 16; i += 256) {
        const int t = i >> 4, d4 = (i & 15) * 4;
        union { u16x4 u; __bf16 b[4]; } kv, vv;
        kv.u = *(const u16x4*)(Kbase + (size_t)(t0 + t) * 3072 + d4);
        vv.u = *(const u16x4*)(Vbase + (size_t)(t0 + t) * 3072 + d4);
        #pragma unroll
        for (int j = 0; j < 4; ++j) {
            Kt[d4 + j][t] = kv.b[j];
            Vt[d4 + j][t] = vv.b[j];
        }
    }
    __syncthreads();

    f32x4 acc[4] = {};
    #pragma unroll
    for (int s = 0; s < CH / 32; ++s) {
        const bf16x8 a = *(const bf16x8*)&Kt[wave * 16 + l15][s * 32 + quad * 8];
        #pragma unroll
        for (int c = 0; c < 4; ++c) {
            const bf16x8 bb = *(const bf16x8*)&Vt[c * 16 + l15][s * 32 + quad * 8];
            acc[c] = __builtin_amdgcn_mfma_f32_16x16x32_bf16(a, bb, acc[c], 0, 0, 0);
        }
    }

    float* Pb = P + ((size_t)chb * 64 + bh) * 4096;
    #pragma unroll
    for (int c = 0; c < 4; ++c)
        *(f32x4*)&Pb[(size_t)(c * 16 + l15) * 64 + wave * 16 + quad * 4] = acc[c];
}

// s_reduce: St[bh][d2][d1] = 0.125 * sum_ch P[ch][bh][d2*64+d1]
__global__ void s_reduce(const float* __restrict__ P, __bf16* __restrict__ St)
{
    const int g = blockIdx.x * 256 + threadIdx.x;   // vec4 index, 65536 total
    f32x4 s = {};
    #pragma unroll
    for (int ch = 0; ch < 16; ++ch)
        s += *(const f32x4*)&P[(size_t)ch * 262144 + (size_t)g * 4];
    bf16x4 o;
    #pragma unroll
    for (int e = 0; e < 4; ++e) o[e] = (__bf16)(s[e] * 0.125f);
    *(bf16x4*)&St[(size_t)g * 4] = o;
}

// ---------------------------------------------------------------------------
// Y kernel: Y[b,t,h*64+d2] = sum_d1 Q[b,t,h,d1] * St[bh][d2][d1]
// Epilogue repacks via LDS for 16B/lane stores (128B runs).
// ---------------------------------------------------------------------------
__global__ void y_kernel(const __bf16* __restrict__ qkv, const __bf16* __restrict__ St,
                         __bf16* __restrict__ Y)
{
    __shared__ __align__(16) __bf16 smem[256 * 72];  // staging 256*64; tile 256x72
    const int bh = blockIdx.y, b = bh >> 4, h = bh & 15;
    const int t0 = blockIdx.x * 256;
    const int tid = threadIdx.x;
    const int wave = tid >> 6, lane = tid & 63;
    const int quad = lane >> 4, l15 = lane & 15;
    const int lrow = lane >> 3, lcol = lane & 7;
    const __bf16* Qb = qkv + ((size_t)b * 2048 + t0) * 3072 + h * 64;

    #pragma unroll
    for (int j = 0; j < 8; ++j) {
        const int chunk = wave * 8 + j;              // 32 chunks of 8 rows
        const int row = chunk * 8 + lrow;
        ld_g2l16(Qb + (size_t)row * 3072 + lcol * 8, &smem[chunk * 512]);
    }

    f32x4 acc[4][4] = {};
    const __bf16* Sb = St + (size_t)bh * 4096;
    __syncthreads();
    #pragma unroll
    for (int s = 0; s < 2; ++s) {
        bf16x8 af[4], bfr[4];
        #pragma unroll
        for (int r = 0; r < 4; ++r)
            af[r] = *(const bf16x8*)&smem[(wave * 64 + r * 16 + l15) * 64 + s * 32 + quad * 8];
        #pragma unroll
        for (int c = 0; c < 4; ++c)
            bfr[c] = *(const bf16x8*)&Sb[(size_t)(c * 16 + l15) * 64 + s * 32 + quad * 8];
        #pragma unroll
        for (int r = 0; r < 4; ++r)
            #pragma unroll
            for (int c = 0; c < 4; ++c)
                acc[r][c] = __builtin_amdgcn_mfma_f32_16x16x32_bf16(af[r], bfr[c], acc[r][c], 0, 0, 0);
    }

    __syncthreads();
    __bf16 (*Cs)[72] = (__bf16(*)[72])smem;
    #pragma unroll
    for (int r = 0; r < 4; ++r)
        #pragma unroll
        for (int c = 0; c < 4; ++c)
            #pragma unroll
            for (int e = 0; e < 4; ++e)
                Cs[wave * 64 + r * 16 + quad * 4 + e][c * 16 + l15] = (__bf16)acc[r][c][e];
    __syncthreads();
    #pragma unroll
    for (int p = 0; p < 8; ++p) {
        const int i = p * 256 + tid;                 // 2048 chunks of 16B
        const int row = i >> 3, ch = i & 7;
        *(bf16x8*)&Y[((size_t)b * 2048 + t0 + row) * 1024 + h * 64 + ch * 8] =
            *(const bf16x8*)&Cs[row][ch * 8];
    }
}

// ---------------------------------------------------------------------------
__global__ void cvt_bf16(const float* __restrict__ src, __bf16* __restrict__ dst, int n4)
{
    const int i = blockIdx.x * 256 + threadIdx.x;
    if (i >= n4) return;
    const float4 v = ((const float4*)src)[i];
    bf16x4 o = { (__bf16)v.x, (__bf16)v.y, (__bf16)v.z, (__bf16)v.w };
    ((bf16x4*)dst)[i] = o;
}

__global__ void init_x(const float* __restrict__ src, __bf16* __restrict__ xB,
                       float* __restrict__ xF, int n4)
{
    const int i = blockIdx.x * 256 + threadIdx.x;
    if (i >= n4) return;
    const float4 v = ((const float4*)src)[i];
    ((float4*)xF)[i] = v;
    bf16x4 o = { (__bf16)v.x, (__bf16)v.y, (__bf16)v.z, (__bf16)v.w };
    ((bf16x4*)xB)[i] = o;
}

// ---------------------------------------------------------------------------
extern "C" void kernel_launch(void* const* d_in, const int* in_sizes, int n_in,
                              void* d_out, int out_size, void* d_ws, size_t ws_size,
                              hipStream_t stream)
{
    const float* x0    = (const float*)d_in[0];   // [4,2048,1024]
    const float* Wqkv  = (const float*)d_in[1];   // [12,3072,1024]
    const float* bqkv  = (const float*)d_in[2];   // [12,3072]
    const float* Wproj = (const float*)d_in[3];   // [12,1024,1024]
    const float* bproj = (const float*)d_in[4];   // [12,1024]
    float* xF = (float*)d_out;                    // fp32 x lives in d_out

    char* p = (char*)d_ws;
    __bf16* WqkvB  = (__bf16*)p; p += (size_t)12 * 3072 * 1024 * 2;  // 75.5 MB
    __bf16* WprojB = (__bf16*)p; p += (size_t)12 * 1024 * 1024 * 2;  // 25.2 MB
    __bf16* xB     = (__bf16*)p; p += (size_t)8192 * 1024 * 2;       // 16.8 MB
    __bf16* qkv    = (__bf16*)p; p += (size_t)8192 * 3072 * 2;       // 50.3 MB
    __bf16* St     = (__bf16*)p; p += (size_t)64 * 4096 * 2;         // 0.5 MB
    __bf16* Y      = (__bf16*)p; p += (size_t)8192 * 1024 * 2;       // 16.8 MB
    float*  Pp     = (float*)p;  p += (size_t)16 * 64 * 4096 * 4;    // 16.8 MB

    cvt_bf16<<<36864, 256, 0, stream>>>(Wqkv, WqkvB, 9437184);
    cvt_bf16<<<12288, 256, 0, stream>>>(Wproj, WprojB, 3145728);
    init_x<<<8192, 256, 0, stream>>>(x0, xB, xF, 2097152);

    for (int i = 0; i < 12; ++i) {
        // qkv = x @ Wqkv^T + bqkv                      [8192,3072]
        gemm_bt<0><<<dim3(24, 64), 256, 0, stream>>>(
            xB, WqkvB + (size_t)i * 3072 * 1024, bqkv + i * 3072,
            qkv, nullptr, 8192, 3072, 1024);
        // partial K^T V over 16 t-chunks, then reduce  [64,64,64]
        s_partial<<<dim3(64, 16), 256, 0, stream>>>(qkv, Pp);
        s_reduce<<<256, 256, 0, stream>>>(Pp, St);
        // Y = Q @ S                                    [8192,1024]
        y_kernel<<<dim3(8, 64), 256, 0, stream>>>(qkv, St, Y);
        // x = x + Y @ Wproj^T + bproj  (fp32 master + bf16 copy)
        gemm_bt<1><<<dim3(8, 64), 256, 0, stream>>>(
            Y, WprojB + (size_t)i * 1024 * 1024, bproj + i * 1024,
            xB, xF, 8192, 1024, 1024);
    }
}